// Round 1
// baseline (190.454 us; speedup 1.0000x reference)
//
#include <hip/hip_runtime.h>

// Problem constants (from reference)
#define V_THRESH 1.0f
#define TAU_REFRAC 0.1f
// N = 32*128*64*64 = 16777216

// Monotone map: float -> uint such that uint compare == float compare.
__device__ __forceinline__ unsigned int map_f32(float f) {
    unsigned int u = __float_as_uint(f);
    return (u & 0x80000000u) ? ~u : (u | 0x80000000u);
}

__global__ void init_max_kernel(unsigned int* ws_max) {
    *ws_max = 0u;  // mapped value of "most negative" -> identity for max
}

__device__ __forceinline__ void neuron(float imp, float me, float rf,
                                       float pl, float ps, float sc,
                                       float t, float t_refrac_end,
                                       float& o_sp, float& o_mem, float& o_rf,
                                       float& o_pl, float& o_ps, float& o_sc,
                                       float& o_st, float& lmax) {
    float mi = (rf > t) ? 0.0f : imp;          // masked impulse
    float nm = me + mi;                         // new_mem
    bool spiked = (nm >= V_THRESH);
    float sp = spiked ? 1.0f : 0.0f;
    o_sp  = sp * V_THRESH;                      // output spikes
    o_mem = nm - V_THRESH * sp;                 // reset by subtraction (neg never fires)
    float resid = nm - V_THRESH;
    float new_pl = resid - ps;                  // two-step, matches reference rounding
    o_pl = spiked ? new_pl : pl;
    o_ps = spiked ? (ps + new_pl) : ps;
    o_rf = spiked ? t_refrac_end : rf;
    o_sc = sc + sp;
    o_st = t * sp;
    lmax = fmaxf(lmax, o_sc);
}

__global__ __launch_bounds__(256) void spike_kernel(
    const float4* __restrict__ impulse,
    const float4* __restrict__ mem,
    const float4* __restrict__ refrac,
    const float4* __restrict__ payloads,
    const float4* __restrict__ paysum,
    const float4* __restrict__ spikecounts,
    const float* __restrict__ time,
    float4* __restrict__ out,          // 7 contiguous output planes, n4 float4 each
    unsigned int* __restrict__ ws_max,
    int n4)
{
    const float t = time[0];
    const float t_end = t + TAU_REFRAC;

    float4* __restrict__ o_sp  = out;
    float4* __restrict__ o_mem = out + (size_t)n4;
    float4* __restrict__ o_rf  = out + 2 * (size_t)n4;
    float4* __restrict__ o_pl  = out + 3 * (size_t)n4;
    float4* __restrict__ o_ps  = out + 4 * (size_t)n4;
    float4* __restrict__ o_sc  = out + 5 * (size_t)n4;
    float4* __restrict__ o_st  = out + 6 * (size_t)n4;

    float lmax = -__builtin_inff();
    const size_t stride = (size_t)gridDim.x * blockDim.x;
    for (size_t i = (size_t)blockIdx.x * blockDim.x + threadIdx.x;
         i < (size_t)n4; i += stride) {
        float4 im = impulse[i];
        float4 me = mem[i];
        float4 rf = refrac[i];
        float4 pl = payloads[i];
        float4 ps = paysum[i];
        float4 sc = spikecounts[i];
        float4 vsp, vmem, vrf, vpl, vps, vsc, vst;

        neuron(im.x, me.x, rf.x, pl.x, ps.x, sc.x, t, t_end,
               vsp.x, vmem.x, vrf.x, vpl.x, vps.x, vsc.x, vst.x, lmax);
        neuron(im.y, me.y, rf.y, pl.y, ps.y, sc.y, t, t_end,
               vsp.y, vmem.y, vrf.y, vpl.y, vps.y, vsc.y, vst.y, lmax);
        neuron(im.z, me.z, rf.z, pl.z, ps.z, sc.z, t, t_end,
               vsp.z, vmem.z, vrf.z, vpl.z, vps.z, vsc.z, vst.z, lmax);
        neuron(im.w, me.w, rf.w, pl.w, ps.w, sc.w, t, t_end,
               vsp.w, vmem.w, vrf.w, vpl.w, vps.w, vsc.w, vst.w, lmax);

        o_sp[i]  = vsp;
        o_mem[i] = vmem;
        o_rf[i]  = vrf;
        o_pl[i]  = vpl;
        o_ps[i]  = vps;
        o_sc[i]  = vsc;
        o_st[i]  = vst;
    }

    // 64-lane butterfly max reduce, one atomic per wave
    #pragma unroll
    for (int off = 32; off > 0; off >>= 1)
        lmax = fmaxf(lmax, __shfl_xor(lmax, off));
    if ((threadIdx.x & 63) == 0)
        atomicMax(ws_max, map_f32(lmax));
}

__global__ void finalize_kernel(const unsigned int* __restrict__ ws_max,
                                const float* __restrict__ time,
                                float* __restrict__ out_scalar) {
    unsigned int m = *ws_max;
    unsigned int u = (m & 0x80000000u) ? (m & 0x7fffffffu) : ~m;
    float v = __uint_as_float(u);
    // max_spikerate = max(spikecounts_out) * DT / t, DT = 1.0
    out_scalar[0] = v * (1.0f / time[0]);
}

extern "C" void kernel_launch(void* const* d_in, const int* in_sizes, int n_in,
                              void* d_out, int out_size, void* d_ws, size_t ws_size,
                              hipStream_t stream) {
    const float4* impulse     = (const float4*)d_in[0];
    const float4* mem         = (const float4*)d_in[1];
    const float4* refrac      = (const float4*)d_in[2];
    const float4* payloads    = (const float4*)d_in[3];
    const float4* paysum      = (const float4*)d_in[4];
    const float4* spikecounts = (const float4*)d_in[5];
    const float*  time        = (const float*)d_in[6];

    const int n  = in_sizes[0];      // 16777216
    const int n4 = n / 4;
    float* out = (float*)d_out;
    unsigned int* ws_max = (unsigned int*)d_ws;

    init_max_kernel<<<1, 1, 0, stream>>>(ws_max);
    spike_kernel<<<2048, 256, 0, stream>>>(impulse, mem, refrac, payloads,
                                           paysum, spikecounts, time,
                                           (float4*)out, ws_max, n4);
    finalize_kernel<<<1, 1, 0, stream>>>(ws_max, time, out + 7 * (size_t)n);
}